// Round 7
// baseline (393.968 us; speedup 1.0000x reference)
//
#include <hip/hip_runtime.h>
#include <hip/hip_bf16.h>

#define NN 16384
#define DD 256

typedef unsigned short u16;
typedef unsigned int u32;
typedef unsigned char u8;
typedef long i64;
typedef __attribute__((ext_vector_type(4))) float f32x4;
typedef __attribute__((ext_vector_type(4))) int i32x4;
typedef __attribute__((ext_vector_type(8))) int i32x8;

// ---------- kernel 1: fp8 e4m3 convert, LDS-transposed, all-coalesced ----------
// (verbatim from R6 -- measured clean, absmax 0. Non-gemm time is invariant
// ~60-65 us across all rounds regardless of prep design => fixed overhead,
// stop optimizing prep.)
// A8 and B8 share ONE fragment-linear layout:
//   addr = pn<<15 | k2<<14 | r8<<11 | jj<<10 | qq<<8 | mm<<4 | u
//   holding fp8 of row (pn*128 + r8*16 + mm), kbyte (k2*128 + qq*32 + jj*16 + u).
__global__ __launch_bounds__(256) void prep_kernel(
        const float* __restrict__ img, const float* __restrict__ txt,
        u8* __restrict__ A8, u8* __restrict__ B8,
        float* __restrict__ zbuf /* s_row..s_col 32768 f */,
        float* __restrict__ out) {
    __shared__ u32 sA[16 * 65 + 8];
    __shared__ u32 sB[16 * 65 + 8];
    const int t = threadIdx.x, bi = blockIdx.x;            // bi = 16-row window
    const float4* ib = (const float4*)img + ((size_t)bi << 10);
    const float4* tb = (const float4*)txt + ((size_t)bi << 10);
    const float S = 1.44269504088896f;                     // log2(e) folded into A
    #pragma unroll
    for (int k = 0; k < 4; ++k) {
        const int idx = (k << 8) + t;                      // 0..1023 float4s
        const int row = idx >> 6, col = idx & 63;          // row 0..15, col 0..63
        float4 va = ib[idx];
        int pa = __builtin_amdgcn_cvt_pk_fp8_f32(va.x * S, va.y * S, 0, false);
        pa     = __builtin_amdgcn_cvt_pk_fp8_f32(va.z * S, va.w * S, pa, true);
        sA[row * 65 + col] = (u32)pa;
        float4 vb = tb[idx];
        int pb = __builtin_amdgcn_cvt_pk_fp8_f32(vb.x, vb.y, 0, false);
        pb     = __builtin_amdgcn_cvt_pk_fp8_f32(vb.z, vb.w, pb, true);
        sB[row * 65 + col] = (u32)pb;
    }
    __syncthreads();
    const int w = t >> 6, l = t & 63;
    const int k2 = w >> 1, jj = w & 1, qq = l >> 4, mm = l & 15;
    const int wb = mm * 65 + (k2 << 5) + (qq << 3) + (jj << 2);
    i32x4 oa = { (int)sA[wb], (int)sA[wb + 1], (int)sA[wb + 2], (int)sA[wb + 3] };
    i32x4 ob = { (int)sB[wb], (int)sB[wb + 1], (int)sB[wb + 2], (int)sB[wb + 3] };
    const size_t dst = ((size_t)(bi >> 3) << 15) + (k2 << 14) + ((size_t)(bi & 7) << 11)
                     + (jj << 10) + (qq << 8) + (mm << 4);
    *(i32x4*)(A8 + dst) = oa;
    *(i32x4*)(B8 + dst) = ob;
    const int gid = (bi << 8) + t;
    if (gid < 32768) zbuf[gid] = 0.0f;
    if (gid == 0) out[0] = 0.0f;
}

// ---------- kernel 2: MX-scaled fp8 GEMM + exp2 + row/col sum + diag ----------
// vs R6 (85 us, MfmaUtil 33%, VALUBusy 49%): INTRA-WAVE EPILOGUE PIPELINE (T15).
// R6 ran load -> MFMA -> epilogue serially per wave; the 2 waves/SIMD run
// identical code and stay in phase, so the matrix pipe idles during the
// exp2/reduce epilogue (wall 6.4k cyc/tile vs 2.2k MFMA + 3.1k VALU).
// Now: two named acc banks; epilogue(tile t-1) sits adjacent to MFMA(tile t)
// in one basic block -- the scheduler slots ~1000 independent VALU/trans ops
// into the ~34-cyc MFMA pipe shadows and into the B-frag L2 latency window.
// setprio REMOVED (it fences motion; we want mixing; isolated value ~0 here).
// bf loaded in cb-pairs (16 regs) to hold total regs ~250 <= 256 (2 waves/SIMD).
// cpart tree vectorized: sum over rb as f32x4 (3 vec adds) then horizontal.
__global__ __launch_bounds__(256, 2) void gemm_lse_kernel(
        const u8* __restrict__ A8, const u8* __restrict__ B8,
        float* __restrict__ s_row, float* __restrict__ s_col,
        float* __restrict__ diag) {
    const int t = threadIdx.x;
    const int lane = t & 63;
    const int w = t >> 6;
    const int wr = w >> 1, wc = w & 1;
    const int q = lane >> 4, m = lane & 15;
    const int bi = blockIdx.x & 127;
    const int jg = blockIdx.x >> 7;
    const int row0 = bi << 7;

    // ---- A fragments direct from global (fragment-linear, coalesced) ----
    const u8* Aw = A8 + ((size_t)bi << 15) + ((size_t)lane << 4);
    i32x8 areg[2][4];
    #pragma unroll
    for (int k2 = 0; k2 < 2; ++k2)
        #pragma unroll
        for (int rb = 0; rb < 4; ++rb) {
            const u8* p = Aw + (k2 << 14) + (((wr << 2) + rb) << 11);
            i32x4 lo = *(const i32x4*)(p);
            i32x4 hi = *(const i32x4*)(p + 1024);
            areg[k2][rb] = __builtin_shufflevector(lo, hi, 0, 1, 2, 3, 4, 5, 6, 7);
        }

    const f32x4 fzero = {0.f, 0.f, 0.f, 0.f};
    f32x4 accA[4][4], accB[4][4];                 // two banks, STATIC names only
    f32x4 rp[4] = {fzero, fzero, fzero, fzero};   // row partials, whole block

    const u8* Bw = B8 + (wc << 13) + ((size_t)lane << 4);

    // MFMA one tile into the given bank (B frags in cb-pairs, 16 regs live)
    auto mfma_tile = [&](f32x4 (&acc)[4][4], int jt_) {
        const int ct = (jg << 4) | ((jt_ + bi) & 15);
        const u8* p = Bw + ((size_t)ct << 15);
        const f32x4 cinit = {-144.f, -144.f, -144.f, -144.f}; // exp2 bias in C
        #pragma unroll
        for (int k2 = 0; k2 < 2; ++k2)
            #pragma unroll
            for (int cp = 0; cp < 2; ++cp) {
                const u8* pp = p + (k2 << 14) + (cp << 12);
                i32x4 lo0 = *(const i32x4*)(pp);
                i32x4 hi0 = *(const i32x4*)(pp + 1024);
                i32x8 bf0 = __builtin_shufflevector(lo0, hi0, 0, 1, 2, 3, 4, 5, 6, 7);
                i32x4 lo1 = *(const i32x4*)(pp + 2048);
                i32x4 hi1 = *(const i32x4*)(pp + 3072);
                i32x8 bf1 = __builtin_shufflevector(lo1, hi1, 0, 1, 2, 3, 4, 5, 6, 7);
                if (k2 == 0) {
                    #pragma unroll
                    for (int rb = 0; rb < 4; ++rb) {
                        acc[rb][2 * cp]     = __builtin_amdgcn_mfma_scale_f32_16x16x128_f8f6f4(
                            areg[0][rb], bf0, cinit, 0, 0, 0, 127, 0, 127);
                        acc[rb][2 * cp + 1] = __builtin_amdgcn_mfma_scale_f32_16x16x128_f8f6f4(
                            areg[0][rb], bf1, cinit, 0, 0, 0, 127, 0, 127);
                    }
                } else {
                    #pragma unroll
                    for (int rb = 0; rb < 4; ++rb) {
                        acc[rb][2 * cp]     = __builtin_amdgcn_mfma_scale_f32_16x16x128_f8f6f4(
                            areg[1][rb], bf0, acc[rb][2 * cp], 0, 0, 0, 127, 0, 127);
                        acc[rb][2 * cp + 1] = __builtin_amdgcn_mfma_scale_f32_16x16x128_f8f6f4(
                            areg[1][rb], bf1, acc[rb][2 * cp + 1], 0, 0, 0, 127, 0, 127);
                    }
                }
            }
    };

    // epilogue for a finished bank (diag, exp2, row/col partials, col atomic)
    auto epilogue = [&](f32x4 (&acc)[4][4], int jt_) {
        const int ct = (jg << 4) | ((jt_ + bi) & 15);
        const int col0 = ct << 7;
        if (bi == ct && wr == wc) {
            #pragma unroll
            for (int rb = 0; rb < 4; ++rb)
                #pragma unroll
                for (int r = 0; r < 4; ++r)
                    if (m == ((q << 2) | r))
                        diag[row0 + (wr << 6) + (rb << 4) + m] = acc[rb][rb][r];
        }
        #pragma unroll
        for (int rb = 0; rb < 4; ++rb)
            #pragma unroll
            for (int cb = 0; cb < 4; ++cb)
                #pragma unroll
                for (int r = 0; r < 4; ++r)
                    acc[rb][cb][r] = __builtin_amdgcn_exp2f(acc[rb][cb][r]);
        #pragma unroll
        for (int rb = 0; rb < 4; ++rb)
            rp[rb] += (acc[rb][0] + acc[rb][1]) + (acc[rb][2] + acc[rb][3]);
        float cpart = 0.0f;
        #pragma unroll
        for (int cb = 0; cb < 4; ++cb) {
            f32x4 s = (acc[0][cb] + acc[1][cb]) + (acc[2][cb] + acc[3][cb]);
            float v = (s[0] + s[1]) + (s[2] + s[3]);
            v += __shfl_xor(v, 16, 64);
            v += __shfl_xor(v, 32, 64);
            if (q == cb) cpart = v;
        }
        atomicAdd(&s_col[col0 + (wc << 6) + (q << 4) + m], cpart);
    };

    // ---- pipelined main loop: epilogue(prev) overlaps MFMA(cur) ----
    mfma_tile(accA, 0);
    #pragma unroll 1
    for (int p7 = 0; p7 < 7; ++p7) {
        mfma_tile(accB, 2 * p7 + 1);
        epilogue (accA, 2 * p7);
        mfma_tile(accA, 2 * p7 + 2);
        epilogue (accB, 2 * p7 + 1);
    }
    mfma_tile(accB, 15);
    epilogue (accA, 14);
    epilogue (accB, 15);

    // ---- block-end row reduction ----
    float rout = 0.0f;
    #pragma unroll
    for (int rb = 0; rb < 4; ++rb)
        #pragma unroll
        for (int r = 0; r < 4; ++r) {
            float v = rp[rb][r];
            v += __shfl_xor(v, 1, 16);
            v += __shfl_xor(v, 2, 16);
            v += __shfl_xor(v, 4, 16);
            v += __shfl_xor(v, 8, 16);
            if (m == ((rb << 2) | r)) rout = v;
        }
    atomicAdd(&s_row[row0 + (wr << 6) + ((m >> 2) << 4) + (q << 2) + (m & 3)], rout);
}

// ---------- kernel 3: final reduce (64 blocks, 256 rows each) ----------
// diag is biased by -144; the +144 LSE un-bias cancels it exactly.
__global__ void final_kernel(const float* __restrict__ s_row, const float* __restrict__ s_col,
                             const float* __restrict__ diag, float* __restrict__ out) {
    __shared__ double red[256];
    int t = threadIdx.x;
    int i = blockIdx.x * 256 + t;
    double p = 0.5 * (double)(log2f(s_row[i]) + log2f(s_col[i])) - (double)diag[i];
    red[t] = p;
    __syncthreads();
    for (int s = 128; s > 0; s >>= 1) {
        if (t < s) red[t] += red[t + s];
        __syncthreads();
    }
    if (t == 0) atomicAdd(out, (float)(red[0] * 0.6931471805599453 / (double)NN));
}

// ---------- launch ----------
extern "C" void kernel_launch(void* const* d_in, const int* in_sizes, int n_in,
                              void* d_out, int out_size, void* d_ws, size_t ws_size,
                              hipStream_t stream) {
    const float* img = (const float*)d_in[0];
    const float* txt = (const float*)d_in[1];
    char* ws = (char*)d_ws;
    u8*    A8    = (u8*)ws;                                // 4 MB
    u8*    B8    = (u8*)(ws + 4194304);                    // 4 MB
    float* s_row = (float*)(ws + 8388608);                 // 64 KB
    float* s_col = (float*)(ws + 8388608 + 65536);         // 64 KB
    float* diag  = (float*)(ws + 8388608 + 131072);        // 64 KB
    float* out   = (float*)d_out;

    prep_kernel<<<1024, 256, 0, stream>>>(img, txt, A8, B8, s_row, out);
    gemm_lse_kernel<<<1024, 256, 0, stream>>>(A8, B8, s_row, s_col, diag);
    final_kernel<<<64, 256, 0, stream>>>(s_row, s_col, diag, out);
}

// Round 8
// 144.656 us; speedup vs baseline: 2.7235x; 2.7235x over previous
//
#include <hip/hip_runtime.h>
#include <hip/hip_bf16.h>

#define NN 16384
#define DD 256

typedef unsigned short u16;
typedef unsigned int u32;
typedef unsigned char u8;
typedef long i64;
typedef __attribute__((ext_vector_type(4))) float f32x4;
typedef __attribute__((ext_vector_type(4))) int i32x4;
typedef __attribute__((ext_vector_type(8))) int i32x8;

// ---------- kernel 1: fp8 e4m3 convert, LDS-transposed, all-coalesced ----------
// (verbatim from R6 -- measured clean, absmax 0.)
// A8 and B8 share ONE fragment-linear layout:
//   addr = pn<<15 | k2<<14 | r8<<11 | jj<<10 | qq<<8 | mm<<4 | u
//   holding fp8 of row (pn*128 + r8*16 + mm), kbyte (k2*128 + qq*32 + jj*16 + u).
__global__ __launch_bounds__(256) void prep_kernel(
        const float* __restrict__ img, const float* __restrict__ txt,
        u8* __restrict__ A8, u8* __restrict__ B8,
        float* __restrict__ zbuf /* s_row..s_col 32768 f */,
        float* __restrict__ out) {
    __shared__ u32 sA[16 * 65 + 8];
    __shared__ u32 sB[16 * 65 + 8];
    const int t = threadIdx.x, bi = blockIdx.x;            // bi = 16-row window
    const float4* ib = (const float4*)img + ((size_t)bi << 10);
    const float4* tb = (const float4*)txt + ((size_t)bi << 10);
    const float S = 1.44269504088896f;                     // log2(e) folded into A
    #pragma unroll
    for (int k = 0; k < 4; ++k) {
        const int idx = (k << 8) + t;                      // 0..1023 float4s
        const int row = idx >> 6, col = idx & 63;          // row 0..15, col 0..63
        float4 va = ib[idx];
        int pa = __builtin_amdgcn_cvt_pk_fp8_f32(va.x * S, va.y * S, 0, false);
        pa     = __builtin_amdgcn_cvt_pk_fp8_f32(va.z * S, va.w * S, pa, true);
        sA[row * 65 + col] = (u32)pa;
        float4 vb = tb[idx];
        int pb = __builtin_amdgcn_cvt_pk_fp8_f32(vb.x, vb.y, 0, false);
        pb     = __builtin_amdgcn_cvt_pk_fp8_f32(vb.z, vb.w, pb, true);
        sB[row * 65 + col] = (u32)pb;
    }
    __syncthreads();
    const int w = t >> 6, l = t & 63;
    const int k2 = w >> 1, jj = w & 1, qq = l >> 4, mm = l & 15;
    const int wb = mm * 65 + (k2 << 5) + (qq << 3) + (jj << 2);
    i32x4 oa = { (int)sA[wb], (int)sA[wb + 1], (int)sA[wb + 2], (int)sA[wb + 3] };
    i32x4 ob = { (int)sB[wb], (int)sB[wb + 1], (int)sB[wb + 2], (int)sB[wb + 3] };
    const size_t dst = ((size_t)(bi >> 3) << 15) + (k2 << 14) + ((size_t)(bi & 7) << 11)
                     + (jj << 10) + (qq << 8) + (mm << 4);
    *(i32x4*)(A8 + dst) = oa;
    *(i32x4*)(B8 + dst) = ob;
    const int gid = (bi << 8) + t;
    if (gid < 32768) zbuf[gid] = 0.0f;
    if (gid == 0) out[0] = 0.0f;
}

// ---------- kernel 2: MX-scaled fp8 GEMM + exp2 + row/col sum + diag ----------
// vs R7 (332 us: full-tile double-bank spilled -- 1.3 GB scratch traffic):
// SAME pipeline idea at HALF-TILE granularity. Per-half acc = 4x2 f32x4 = 32
// VGPR; two banks = 64 = R6's single acc cost. Live regs ~185 -> no spill,
// 2 blocks/CU held. Bank A statically owns column-half h=0 (cb 0,1), bank B
// owns h=1 (cb 2,3) -- all indexing static. Schedule: mfma(next half) sits
// adjacent to epilogue(prev half) in one basic block, so each 16-MFMA cluster
// (~550 cyc matrix pipe) absorbs ~130 independent VALU/trans epilogue ops and
// covers the next B-frag L2 latency. s_col atomic: cpart accumulated across
// the tile's two halves in a register (each lane's q matches exactly one
// half), flushed once per tile in the h=1 epilogue.
__global__ __launch_bounds__(256, 2) void gemm_lse_kernel(
        const u8* __restrict__ A8, const u8* __restrict__ B8,
        float* __restrict__ s_row, float* __restrict__ s_col,
        float* __restrict__ diag) {
    const int t = threadIdx.x;
    const int lane = t & 63;
    const int w = t >> 6;
    const int wr = w >> 1, wc = w & 1;
    const int q = lane >> 4, m = lane & 15;
    const int bi = blockIdx.x & 127;
    const int jg = blockIdx.x >> 7;
    const int row0 = bi << 7;

    // ---- A fragments direct from global (fragment-linear, coalesced) ----
    const u8* Aw = A8 + ((size_t)bi << 15) + ((size_t)lane << 4);
    i32x8 areg[2][4];
    #pragma unroll
    for (int k2 = 0; k2 < 2; ++k2)
        #pragma unroll
        for (int rb = 0; rb < 4; ++rb) {
            const u8* p = Aw + (k2 << 14) + (((wr << 2) + rb) << 11);
            i32x4 lo = *(const i32x4*)(p);
            i32x4 hi = *(const i32x4*)(p + 1024);
            areg[k2][rb] = __builtin_shufflevector(lo, hi, 0, 1, 2, 3, 4, 5, 6, 7);
        }

    const f32x4 fzero = {0.f, 0.f, 0.f, 0.f};
    f32x4 accA[4][2], accB[4][2];                 // half-tile banks, static names
    f32x4 rp[4] = {fzero, fzero, fzero, fzero};   // row partials, whole block
    float cpartT = 0.0f;                          // per-tile col partial

    const u8* Bw = B8 + (wc << 13) + ((size_t)lane << 4);

    // MFMA one column-half (h fixed per bank) into acc: 16 MFMAs, 4 B-frags
    auto mfma_half = [&](f32x4 (&acc)[4][2], int jt_, int h) {
        const int ct = (jg << 4) | ((jt_ + bi) & 15);
        const u8* p = Bw + ((size_t)ct << 15) + (h << 12);
        const f32x4 cinit = {-144.f, -144.f, -144.f, -144.f}; // exp2 bias in C
        #pragma unroll
        for (int k2 = 0; k2 < 2; ++k2) {
            const u8* pp = p + (k2 << 14);
            i32x4 lo0 = *(const i32x4*)(pp);
            i32x4 hi0 = *(const i32x4*)(pp + 1024);
            i32x8 bf0 = __builtin_shufflevector(lo0, hi0, 0, 1, 2, 3, 4, 5, 6, 7);
            i32x4 lo1 = *(const i32x4*)(pp + 2048);
            i32x4 hi1 = *(const i32x4*)(pp + 3072);
            i32x8 bf1 = __builtin_shufflevector(lo1, hi1, 0, 1, 2, 3, 4, 5, 6, 7);
            if (k2 == 0) {
                #pragma unroll
                for (int rb = 0; rb < 4; ++rb) {
                    acc[rb][0] = __builtin_amdgcn_mfma_scale_f32_16x16x128_f8f6f4(
                        areg[0][rb], bf0, cinit, 0, 0, 0, 127, 0, 127);
                    acc[rb][1] = __builtin_amdgcn_mfma_scale_f32_16x16x128_f8f6f4(
                        areg[0][rb], bf1, cinit, 0, 0, 0, 127, 0, 127);
                }
            } else {
                #pragma unroll
                for (int rb = 0; rb < 4; ++rb) {
                    acc[rb][0] = __builtin_amdgcn_mfma_scale_f32_16x16x128_f8f6f4(
                        areg[1][rb], bf0, acc[rb][0], 0, 0, 0, 127, 0, 127);
                    acc[rb][1] = __builtin_amdgcn_mfma_scale_f32_16x16x128_f8f6f4(
                        areg[1][rb], bf1, acc[rb][1], 0, 0, 0, 127, 0, 127);
                }
            }
        }
    };

    // epilogue for a finished half (diag, exp2, row partials, col partial)
    auto epilogue_half = [&](f32x4 (&acc)[4][2], int jt_, int h) {
        const int ct = (jg << 4) | ((jt_ + bi) & 15);
        if (bi == ct && wr == wc) {
            #pragma unroll
            for (int rb = 0; rb < 4; ++rb)
                if ((rb >> 1) == h) {
                    #pragma unroll
                    for (int r = 0; r < 4; ++r)
                        if (m == ((q << 2) | r))
                            diag[row0 + (wr << 6) + (rb << 4) + m] = acc[rb][rb & 1][r];
                }
        }
        #pragma unroll
        for (int rb = 0; rb < 4; ++rb)
            #pragma unroll
            for (int cb = 0; cb < 2; ++cb)
                #pragma unroll
                for (int r = 0; r < 4; ++r)
                    acc[rb][cb][r] = __builtin_amdgcn_exp2f(acc[rb][cb][r]);
        #pragma unroll
        for (int rb = 0; rb < 4; ++rb)
            rp[rb] += acc[rb][0] + acc[rb][1];
        #pragma unroll
        for (int cb = 0; cb < 2; ++cb) {
            f32x4 s = (acc[0][cb] + acc[1][cb]) + (acc[2][cb] + acc[3][cb]);
            float v = (s[0] + s[1]) + (s[2] + s[3]);
            v += __shfl_xor(v, 16, 64);
            v += __shfl_xor(v, 32, 64);
            if (q == ((h << 1) | cb)) cpartT = v;
        }
        if (h == 1) {
            const int col0 = ct << 7;
            atomicAdd(&s_col[col0 + (wc << 6) + (q << 4) + m], cpartT);
        }
    };

    // ---- pipelined loop: mfma(next half) || epilogue(prev half) ----
    mfma_half(accA, 0, 0);
    #pragma unroll 1
    for (int jt = 0; jt < 15; ++jt) {
        mfma_half(accB, jt, 1);
        epilogue_half(accA, jt, 0);
        mfma_half(accA, jt + 1, 0);
        epilogue_half(accB, jt, 1);
    }
    mfma_half(accB, 15, 1);
    epilogue_half(accA, 15, 0);
    epilogue_half(accB, 15, 1);

    // ---- block-end row reduction ----
    float rout = 0.0f;
    #pragma unroll
    for (int rb = 0; rb < 4; ++rb)
        #pragma unroll
        for (int r = 0; r < 4; ++r) {
            float v = rp[rb][r];
            v += __shfl_xor(v, 1, 16);
            v += __shfl_xor(v, 2, 16);
            v += __shfl_xor(v, 4, 16);
            v += __shfl_xor(v, 8, 16);
            if (m == ((rb << 2) | r)) rout = v;
        }
    atomicAdd(&s_row[row0 + (wr << 6) + ((m >> 2) << 4) + (q << 2) + (m & 3)], rout);
}

// ---------- kernel 3: final reduce (64 blocks, 256 rows each) ----------
// diag is biased by -144; the +144 LSE un-bias cancels it exactly.
__global__ void final_kernel(const float* __restrict__ s_row, const float* __restrict__ s_col,
                             const float* __restrict__ diag, float* __restrict__ out) {
    __shared__ double red[256];
    int t = threadIdx.x;
    int i = blockIdx.x * 256 + t;
    double p = 0.5 * (double)(log2f(s_row[i]) + log2f(s_col[i])) - (double)diag[i];
    red[t] = p;
    __syncthreads();
    for (int s = 128; s > 0; s >>= 1) {
        if (t < s) red[t] += red[t + s];
        __syncthreads();
    }
    if (t == 0) atomicAdd(out, (float)(red[0] * 0.6931471805599453 / (double)NN));
}

// ---------- launch ----------
extern "C" void kernel_launch(void* const* d_in, const int* in_sizes, int n_in,
                              void* d_out, int out_size, void* d_ws, size_t ws_size,
                              hipStream_t stream) {
    const float* img = (const float*)d_in[0];
    const float* txt = (const float*)d_in[1];
    char* ws = (char*)d_ws;
    u8*    A8    = (u8*)ws;                                // 4 MB
    u8*    B8    = (u8*)(ws + 4194304);                    // 4 MB
    float* s_row = (float*)(ws + 8388608);                 // 64 KB
    float* s_col = (float*)(ws + 8388608 + 65536);         // 64 KB
    float* diag  = (float*)(ws + 8388608 + 131072);        // 64 KB
    float* out   = (float*)d_out;

    prep_kernel<<<1024, 256, 0, stream>>>(img, txt, A8, B8, s_row, out);
    gemm_lse_kernel<<<1024, 256, 0, stream>>>(A8, B8, s_row, s_col, diag);
    final_kernel<<<64, 256, 0, stream>>>(s_row, s_col, diag, out);
}